// Round 1
// baseline (200.700 us; speedup 1.0000x reference)
//
#include <hip/hip_runtime.h>

#define BATCH 32
#define CH    256
#define HWPX  3136   // 56*56
#define WIDTH 56
#define NK    16
#define EPSV  1e-5f

// ---------------------------------------------------------------------------
// Kernel 1: K[b,n,k] = sum_c k_w[k,c] * BN(x[b,c,n])
// grid: 32*13 blocks, 256 threads; thread = one pixel (coalesced over c-steps)
// k_w reads are wave-uniform -> s_load_dwordx4 (scalar cache), no LDS.
// ---------------------------------------------------------------------------
__global__ __launch_bounds__(256) void kkvec(
    const float* __restrict__ x,
    const float* __restrict__ gamma, const float* __restrict__ beta,
    const float* __restrict__ mean,  const float* __restrict__ var,
    const float* __restrict__ kw,    float* __restrict__ Kbuf)
{
    const int b  = blockIdx.x / 13;
    const int nb = blockIdx.x % 13;
    const int px = nb * 256 + threadIdx.x;
    const bool valid = (px < HWPX);
    const int pxc = valid ? px : (HWPX - 1);
    const float* xp = x + (size_t)b * CH * HWPX + pxc;

    float acc[NK];
#pragma unroll
    for (int k = 0; k < NK; ++k) acc[k] = 0.f;

    for (int c0 = 0; c0 < CH; c0 += 4) {
        float v[4];
#pragma unroll
        for (int cc = 0; cc < 4; ++cc) {
            const int c = c0 + cc;
            const float sc = gamma[c] * rsqrtf(var[c] + EPSV);
            const float sh = fmaf(-mean[c], sc, beta[c]);
            v[cc] = fmaf(xp[(size_t)c * HWPX], sc, sh);
        }
#pragma unroll
        for (int k = 0; k < NK; ++k) {
            const float4 wv = *(const float4*)(kw + k * CH + c0); // uniform -> s_load
            acc[k] = fmaf(v[0], wv.x, acc[k]);
            acc[k] = fmaf(v[1], wv.y, acc[k]);
            acc[k] = fmaf(v[2], wv.z, acc[k]);
            acc[k] = fmaf(v[3], wv.w, acc[k]);
        }
    }
    if (valid) {
        float4* Kp = (float4*)(Kbuf + ((size_t)b * HWPX + px) * NK);
#pragma unroll
        for (int kq = 0; kq < 4; ++kq)
            Kp[kq] = make_float4(acc[kq*4+0], acc[kq*4+1], acc[kq*4+2], acc[kq*4+3]);
    }
}

// ---------------------------------------------------------------------------
// Kernel 2: P_part[b,nb,c,k] = sum_{n in slab} BN(x[b,c,n]) * K[b,n,k]
// grid: 32*14 blocks (224-pixel slabs), 256 threads; thread = channel row.
// K reads are wave-uniform -> scalar loads; x streamed as float4 per row.
// ---------------------------------------------------------------------------
__global__ __launch_bounds__(256) void kpmat(
    const float* __restrict__ x,
    const float* __restrict__ gamma, const float* __restrict__ beta,
    const float* __restrict__ mean,  const float* __restrict__ var,
    const float* __restrict__ Kbuf,  float* __restrict__ Pp)
{
    const int b  = blockIdx.x / 14;
    const int nb = blockIdx.x % 14;
    const int n0 = nb * 224;
    const int c  = threadIdx.x;

    const float sc = gamma[c] * rsqrtf(var[c] + EPSV);
    const float sh = fmaf(-mean[c], sc, beta[c]);

    const float4* xr = (const float4*)(x + ((size_t)b * CH + c) * HWPX + n0);
    const float*  Kp = Kbuf + ((size_t)b * HWPX + n0) * NK;

    float acc[NK];
#pragma unroll
    for (int k = 0; k < NK; ++k) acc[k] = 0.f;

    for (int j = 0; j < 56; ++j) {
        const float4 xv = xr[j];
        float v[4];
        v[0] = fmaf(xv.x, sc, sh); v[1] = fmaf(xv.y, sc, sh);
        v[2] = fmaf(xv.z, sc, sh); v[3] = fmaf(xv.w, sc, sh);
#pragma unroll
        for (int d = 0; d < 4; ++d) {
            const float vd = v[d];
#pragma unroll
            for (int kq = 0; kq < 4; ++kq) {
                const float4 kv = *(const float4*)(Kp + ((j*4 + d) * NK) + kq*4); // uniform
                acc[kq*4+0] = fmaf(vd, kv.x, acc[kq*4+0]);
                acc[kq*4+1] = fmaf(vd, kv.y, acc[kq*4+1]);
                acc[kq*4+2] = fmaf(vd, kv.z, acc[kq*4+2]);
                acc[kq*4+3] = fmaf(vd, kv.w, acc[kq*4+3]);
            }
        }
    }
    float4* op = (float4*)(Pp + (((size_t)b * 14 + nb) * CH + c) * NK);
#pragma unroll
    for (int kq = 0; kq < 4; ++kq)
        op[kq] = make_float4(acc[kq*4+0], acc[kq*4+1], acc[kq*4+2], acc[kq*4+3]);
}

// ---------------------------------------------------------------------------
// Kernel 3: reduce P partials; S = q_w @ P; attn = softmax(S/512) over k;
//           wgt[b,c,:] = attn @ kernel_bank.  grid: 32*8 blocks (32 c's each).
// ---------------------------------------------------------------------------
__global__ __launch_bounds__(256) void ksoft(
    const float* __restrict__ Pp, const float* __restrict__ qw,
    const float* __restrict__ bank, float* __restrict__ wgt)
{
    const int b  = blockIdx.x >> 3;
    const int cb = blockIdx.x & 7;
    const int tid = threadIdx.x;

    __shared__ float s_P[CH * NK];       // full P[b] (16 KB)
    __shared__ float s_red[32 * 8 * NK]; // partial S (16 KB)
    __shared__ float s_S[32 * NK];
    __shared__ float s_attn[32 * NK];

    // reduce 14 slabs -> full P for this batch
    for (int idx = tid; idx < CH * NK; idx += 256) {
        float s = 0.f;
        for (int nb = 0; nb < 14; ++nb)
            s += Pp[((size_t)b * 14 + nb) * (CH * NK) + idx];
        s_P[idx] = s;
    }
    __syncthreads();

    // S[c,k] partials over c' ranges of 32
    const int c_l = tid & 31, sub = tid >> 5;
    const int c = cb * 32 + c_l;
    float a[NK];
#pragma unroll
    for (int k = 0; k < NK; ++k) a[k] = 0.f;
    const float* qrow = qw + (size_t)c * CH + sub * 32;
    for (int j = 0; j < 32; ++j) {
        const float qv = qrow[j];
        const float4* p4 = (const float4*)&s_P[(sub * 32 + j) * NK];
#pragma unroll
        for (int kq = 0; kq < 4; ++kq) {
            const float4 pv = p4[kq];
            a[kq*4+0] = fmaf(qv, pv.x, a[kq*4+0]);
            a[kq*4+1] = fmaf(qv, pv.y, a[kq*4+1]);
            a[kq*4+2] = fmaf(qv, pv.z, a[kq*4+2]);
            a[kq*4+3] = fmaf(qv, pv.w, a[kq*4+3]);
        }
    }
#pragma unroll
    for (int kq = 0; kq < 4; ++kq)
        *(float4*)&s_red[(c_l * 8 + sub) * NK + kq*4] =
            make_float4(a[kq*4+0], a[kq*4+1], a[kq*4+2], a[kq*4+3]);
    __syncthreads();

    // reduce subs -> logits (already /512)
    for (int idx = tid; idx < 32 * NK; idx += 256) {
        const int cl = idx >> 4, k = idx & 15;
        float s = 0.f;
#pragma unroll
        for (int s2 = 0; s2 < 8; ++s2) s += s_red[(cl * 8 + s2) * NK + k];
        s_S[idx] = s * (1.f / 512.f);
    }
    __syncthreads();

    if (tid < 32) {
        float l[NK];
#pragma unroll
        for (int k = 0; k < NK; ++k) l[k] = s_S[tid * NK + k];
        float m = l[0];
#pragma unroll
        for (int k = 1; k < NK; ++k) m = fmaxf(m, l[k]);
        float sum = 0.f;
#pragma unroll
        for (int k = 0; k < NK; ++k) { l[k] = __expf(l[k] - m); sum += l[k]; }
        const float inv = 1.f / sum;
#pragma unroll
        for (int k = 0; k < NK; ++k) s_attn[tid * NK + k] = l[k] * inv;
    }
    __syncthreads();

    // wgt[c,e] = sum_k attn[c,k] * bank[k,e]
    for (int idx = tid; idx < 32 * 49; idx += 256) {
        const int cl = idx / 49, e = idx - cl * 49;
        float wv = 0.f;
#pragma unroll
        for (int k = 0; k < NK; ++k)
            wv = fmaf(s_attn[cl * NK + k], bank[k * 49 + e], wv);
        wgt[((size_t)b * CH + cb * 32 + cl) * 49 + e] = wv;
    }
}

// ---------------------------------------------------------------------------
// Kernel 4: depthwise 7x7 'same' conv, per-(b,c) dynamic kernel + bias.
// grid: 8192 blocks (one 56x56 plane), 256 threads; thread = 4x4 output tile.
// Plane staged in LDS [62][64] (zero halo, float4-aligned reads), 49 w in VGPRs.
// ---------------------------------------------------------------------------
__global__ __launch_bounds__(256) void kconv(
    const float* __restrict__ x, const float* __restrict__ wgt,
    const float* __restrict__ bias, float* __restrict__ out)
{
    const int bc  = blockIdx.x;
    const int cch = bc & 255;
    const int tid = threadIdx.x;

    __shared__ __align__(16) float s_p[62 * 64];
    __shared__ float s_w[64];

    const float4 z4 = make_float4(0.f, 0.f, 0.f, 0.f);
    for (int i = tid; i < (62 * 64) / 4; i += 256) ((float4*)s_p)[i] = z4;
    if (tid < 49) s_w[tid] = wgt[(size_t)bc * 49 + tid];
    __syncthreads();

    const float4* xp4 = (const float4*)(x + (size_t)bc * HWPX);
    for (int i = tid; i < 784; i += 256) {
        const float4 v = xp4[i];
        const int y = i / 14, q = i - y * 14;
        float* dst = &s_p[(y + 3) * 64 + 4 * q + 3];
        dst[0] = v.x; dst[1] = v.y; dst[2] = v.z; dst[3] = v.w;
    }
    __syncthreads();

    float w[49];
#pragma unroll
    for (int i = 0; i < 49; ++i) w[i] = s_w[i];
    const float bv = bias[cch];

    if (tid < 196) {
        const int ty = (tid / 14) * 4, tx = (tid % 14) * 4;
        float acc[16];
#pragma unroll
        for (int i = 0; i < 16; ++i) acc[i] = bv;

#pragma unroll
        for (int ri = 0; ri < 10; ++ri) {
            const float* row = &s_p[(ty + ri) * 64 + tx];
            const float4 r0 = *(const float4*)(row);
            const float4 r1 = *(const float4*)(row + 4);
            const float4 r2 = *(const float4*)(row + 8);
            float rr[12];
            rr[0]=r0.x; rr[1]=r0.y; rr[2]=r0.z;  rr[3]=r0.w;
            rr[4]=r1.x; rr[5]=r1.y; rr[6]=r1.z;  rr[7]=r1.w;
            rr[8]=r2.x; rr[9]=r2.y; rr[10]=r2.z; rr[11]=r2.w;
#pragma unroll
            for (int iy = 0; iy < 4; ++iy) {
                const int ky = ri - iy;
                if (ky < 0 || ky > 6) continue;   // compile-time pruned
#pragma unroll
                for (int ix = 0; ix < 4; ++ix) {
#pragma unroll
                    for (int kx = 0; kx < 7; ++kx)
                        acc[iy*4+ix] = fmaf(w[ky*7+kx], rr[kx+ix], acc[iy*4+ix]);
                }
            }
        }
#pragma unroll
        for (int iy = 0; iy < 4; ++iy) {
            float* op = out + (size_t)bc * HWPX + (ty + iy) * WIDTH + tx;
            *(float4*)op = make_float4(acc[iy*4+0], acc[iy*4+1], acc[iy*4+2], acc[iy*4+3]);
        }
    }
}

// ---------------------------------------------------------------------------
extern "C" void kernel_launch(void* const* d_in, const int* in_sizes, int n_in,
                              void* d_out, int out_size, void* d_ws, size_t ws_size,
                              hipStream_t stream)
{
    const float* x     = (const float*)d_in[0];
    const float* gamma = (const float*)d_in[1];
    const float* beta  = (const float*)d_in[2];
    const float* mean  = (const float*)d_in[3];
    const float* var   = (const float*)d_in[4];
    const float* qw    = (const float*)d_in[5];
    const float* kw    = (const float*)d_in[6];
    const float* bank  = (const float*)d_in[7];
    const float* bias  = (const float*)d_in[8];
    float* out = (float*)d_out;

    float* ws   = (float*)d_ws;
    float* Kbuf = ws;                                   // 32*3136*16 = 1,605,632 f
    float* Pp   = Kbuf + (size_t)BATCH * HWPX * NK;     // 32*14*256*16 = 1,835,008 f
    float* wgt  = Pp + (size_t)BATCH * 14 * CH * NK;    // 32*256*49   =   401,408 f

    kkvec<<<dim3(BATCH * 13), dim3(256), 0, stream>>>(x, gamma, beta, mean, var, kw, Kbuf);
    kpmat<<<dim3(BATCH * 14), dim3(256), 0, stream>>>(x, gamma, beta, mean, var, Kbuf, Pp);
    ksoft<<<dim3(BATCH * 8),  dim3(256), 0, stream>>>(Pp, qw, bank, wgt);
    kconv<<<dim3(BATCH * CH), dim3(256), 0, stream>>>(x, wgt, bias, out);
}